// Round 2
// baseline (1925.719 us; speedup 1.0000x reference)
//
#include <hip/hip_runtime.h>
#include <hip/hip_bf16.h>
#include <stdint.h>

// Problem constants
// B=16, C=1024, D=H=W=8 -> N=512 tokens, 27 taps
#define BATCH 16
#define CCH   1024
#define NTOK  512

typedef _Float16 f16_t;
typedef f16_t f16x8 __attribute__((ext_vector_type(8)));
typedef f16_t f16x4 __attribute__((ext_vector_type(4)));
typedef float f32x4 __attribute__((ext_vector_type(4)));

#define GAS __attribute__((address_space(1)))
#define LAS __attribute__((address_space(3)))

__device__ __forceinline__ void gload_lds16(const void* g, void* l) {
  __builtin_amdgcn_global_load_lds((const GAS uint32_t*)g, (LAS uint32_t*)l, 16, 0, 0);
}

// ---------------- cast + transpose: [B][C][N] f32 -> [B][N][C] f16 -----------
__global__ __launch_bounds__(256) void cast_transpose_kernel(
    const float* __restrict__ src, f16_t* __restrict__ dst) {
  __shared__ float tile[64][65];
  const int b  = blockIdx.z;
  const int c0 = blockIdx.y * 64;
  const int n0 = blockIdx.x * 64;
  const int col  = threadIdx.x & 63;
  const int row4 = threadIdx.x >> 6;  // 0..3
  const float* s = src + ((size_t)b * CCH + c0) * NTOK + n0;
#pragma unroll
  for (int r = 0; r < 64; r += 4)
    tile[r + row4][col] = s[(size_t)(r + row4) * NTOK + col];
  __syncthreads();
  f16_t* d = dst + ((size_t)b * NTOK + n0) * CCH + c0;
#pragma unroll
  for (int r = 0; r < 64; r += 4)
    d[(size_t)(r + row4) * CCH + col] = (f16_t)tile[col][r + row4];
}

// ---------------- weight transpose: [O][I][27] f32 -> [27][O][I] f16 ---------
__global__ __launch_bounds__(256) void wtrans_kernel(
    const float* __restrict__ w, f16_t* __restrict__ wt) {
  __shared__ float buf[64 * 27];
  const int o  = blockIdx.x;
  const int i0 = blockIdx.y * 64;
  const float* s = w + (size_t)o * (CCH * 27) + (size_t)i0 * 27;
  for (int idx = threadIdx.x; idx < 64 * 27; idx += 256) buf[idx] = s[idx];
  __syncthreads();
  for (int idx = threadIdx.x; idx < 64 * 27; idx += 256) {
    const int t = idx >> 6;   // 0..26
    const int i = idx & 63;
    wt[((size_t)t * CCH + o) * CCH + i0 + i] = (f16_t)buf[i * 27 + t];
  }
}

// ---------------- conv as 27 shifted GEMMs, 128x128 tile, BK=64 --------------
// src: [B][N][C] f16 (x_t or y_t);  wt: [27][O][I] f16;  bias: [O] f32
// v_layout==0: out [B][N][O] f16 (q,k);  v_layout==1: out [B][O][N] f16 (v)
__global__ __launch_bounds__(256) void conv_gemm_kernel(
    const f16_t* __restrict__ src, const f16_t* __restrict__ wt,
    const float* __restrict__ bias, f16_t* __restrict__ outT,
    const int v_layout, const f16_t* __restrict__ zeropage) {
  __shared__ f16_t As[128 * 64];
  __shared__ f16_t Bs[128 * 64];
  char* As_c = (char*)As;
  char* Bs_c = (char*)Bs;

  const int tid  = threadIdx.x;
  const int lane = tid & 63;
  const int wave = tid >> 6;
  const int wr = wave >> 1, wc = wave & 1;

  const int m0  = blockIdx.y * 128;   // C_out base
  const int bn0 = blockIdx.x * 128;   // global (b*512+n) base
  const int b   = bn0 >> 9;
  const int n0  = bn0 & 511;

  // staging geometry: round r stages rows r*32..r*32+31, 8 lanes x 16B per row
  const int rowb = tid >> 3;          // 0..31
  const int colb = (tid & 7) * 16;    // byte col within 128B row

  const char* arowp[4];
  int nrow[4];
#pragma unroll
  for (int r = 0; r < 4; ++r) {
    const int row = r * 32 + rowb;
    arowp[r] = (const char*)(wt + (size_t)(m0 + row) * CCH) + colb;
    nrow[r]  = n0 + row;
  }

  f32x4 acc[4][4] = {};

  const int fr = lane & 15;
  const int fk = (lane >> 4) << 3;

  for (int kt = 0; kt < 27; ++kt) {
    const int kd = kt / 9, kh = (kt / 3) % 3, kw = kt % 3;
    const size_t ktoff = (size_t)kt * (size_t)(CCH * CCH * 2);
    const char* bp[4];
    int badv[4];
#pragma unroll
    for (int r = 0; r < 4; ++r) {
      const int n = nrow[r];
      const int d = (n >> 6) + kd - 1;
      const int h = ((n >> 3) & 7) + kh - 1;
      const int w = (n & 7) + kw - 1;
      const bool ok = ((unsigned)d < 8u) && ((unsigned)h < 8u) && ((unsigned)w < 8u);
      const int nsrc = (d << 6) + (h << 3) + w;
      bp[r] = ok ? (const char*)(src + ((size_t)b * NTOK + nsrc) * CCH) + colb
                 : (const char*)zeropage + colb;
      badv[r] = ok ? 128 : 0;
    }
    for (int k0b = 0; k0b < 2048; k0b += 128) {  // byte offset along K (64 f16)
#pragma unroll
      for (int r = 0; r < 4; ++r)
        gload_lds16(arowp[r] + ktoff + k0b, As_c + r * 4096 + wave * 1024);
#pragma unroll
      for (int r = 0; r < 4; ++r) {
        gload_lds16(bp[r], Bs_c + r * 4096 + wave * 1024);
        bp[r] += badv[r];
      }
      __syncthreads();
#pragma unroll
      for (int ks = 0; ks < 2; ++ks) {
        const int kc = ks * 32 + fk;
        f16x8 av[4], bv[4];
#pragma unroll
        for (int i = 0; i < 4; ++i)
          av[i] = *(const f16x8*)&As[(wr * 64 + i * 16 + fr) * 64 + kc];
#pragma unroll
        for (int i = 0; i < 4; ++i)
          bv[i] = *(const f16x8*)&Bs[(wc * 64 + i * 16 + fr) * 64 + kc];
#pragma unroll
        for (int i = 0; i < 4; ++i)
#pragma unroll
          for (int j = 0; j < 4; ++j)
            acc[i][j] = __builtin_amdgcn_mfma_f32_16x16x32_f16(av[i], bv[j], acc[i][j], 0, 0, 0);
      }
      __syncthreads();
    }
  }

  // epilogue: C[m][n], m = co, n = token. C/D frag: col=lane&15, row=(lane>>4)*4+reg
  const int mo   = m0 + wr * 64 + ((lane >> 4) << 2);
  const int nloc = n0 + wc * 64 + (lane & 15);
  if (v_layout == 0) {
#pragma unroll
    for (int i = 0; i < 4; ++i) {
      const int m = mo + i * 16;
      const float4 bs = *(const float4*)&bias[m];
#pragma unroll
      for (int j = 0; j < 4; ++j) {
        const int n = nloc + j * 16;
        f16x4 pk;
        pk[0] = (f16_t)(acc[i][j][0] + bs.x);
        pk[1] = (f16_t)(acc[i][j][1] + bs.y);
        pk[2] = (f16_t)(acc[i][j][2] + bs.z);
        pk[3] = (f16_t)(acc[i][j][3] + bs.w);
        *(f16x4*)(outT + ((size_t)b * NTOK + n) * CCH + m) = pk;
      }
    }
  } else {
#pragma unroll
    for (int i = 0; i < 4; ++i) {
      const int m = mo + i * 16;
      const float4 bs = *(const float4*)&bias[m];
      const float bb[4] = {bs.x, bs.y, bs.z, bs.w};
#pragma unroll
      for (int reg = 0; reg < 4; ++reg) {
        f16_t* dst = outT + ((size_t)b * CCH + m + reg) * NTOK;
#pragma unroll
        for (int j = 0; j < 4; ++j) {
          const int n = nloc + j * 16;
          dst[n] = (f16_t)(acc[i][j][reg] + bb[reg]);
        }
      }
    }
  }
}

// ---------------- generic gemm_bt for attention: C = A * Bt^T (+resid) -------
// A: [M][Kdim] f16 rows contiguous; Bt: [N][Kdim] f16; C fp32 [M][ldc]
__global__ __launch_bounds__(256) void attn_gemm_kernel(
    const f16_t* __restrict__ A, const f16_t* __restrict__ Bt,
    float* __restrict__ Cout, const float* __restrict__ resid,
    const int Kdim, const int ldc,
    const size_t strideA, const size_t strideB, const size_t strideC) {
  __shared__ f16_t As[128 * 64];
  __shared__ f16_t Bs[128 * 64];
  char* As_c = (char*)As;
  char* Bs_c = (char*)Bs;

  const int tid  = threadIdx.x;
  const int lane = tid & 63;
  const int wave = tid >> 6;
  const int wr = wave >> 1, wc = wave & 1;
  const int bz = blockIdx.z;
  const int m0 = blockIdx.y * 128;
  const int n0 = blockIdx.x * 128;

  const f16_t* Ab = A + (size_t)bz * strideA;
  const f16_t* Bb = Bt + (size_t)bz * strideB;

  const int rowb = tid >> 3;
  const int colb = (tid & 7) * 16;

  const char* ap[4];
  const char* bp[4];
#pragma unroll
  for (int r = 0; r < 4; ++r) {
    const int row = r * 32 + rowb;
    ap[r] = (const char*)(Ab + (size_t)(m0 + row) * Kdim) + colb;
    bp[r] = (const char*)(Bb + (size_t)(n0 + row) * Kdim) + colb;
  }

  f32x4 acc[4][4] = {};
  const int fr = lane & 15;
  const int fk = (lane >> 4) << 3;

  for (int k0 = 0; k0 < Kdim; k0 += 64) {
#pragma unroll
    for (int r = 0; r < 4; ++r)
      gload_lds16(ap[r], As_c + r * 4096 + wave * 1024);
#pragma unroll
    for (int r = 0; r < 4; ++r)
      gload_lds16(bp[r], Bs_c + r * 4096 + wave * 1024);
#pragma unroll
    for (int r = 0; r < 4; ++r) { ap[r] += 128; bp[r] += 128; }
    __syncthreads();
#pragma unroll
    for (int ks = 0; ks < 2; ++ks) {
      const int kc = ks * 32 + fk;
      f16x8 av[4], bv[4];
#pragma unroll
      for (int i = 0; i < 4; ++i)
        av[i] = *(const f16x8*)&As[(wr * 64 + i * 16 + fr) * 64 + kc];
#pragma unroll
      for (int i = 0; i < 4; ++i)
        bv[i] = *(const f16x8*)&Bs[(wc * 64 + i * 16 + fr) * 64 + kc];
#pragma unroll
      for (int i = 0; i < 4; ++i)
#pragma unroll
        for (int j = 0; j < 4; ++j)
          acc[i][j] = __builtin_amdgcn_mfma_f32_16x16x32_f16(av[i], bv[j], acc[i][j], 0, 0, 0);
    }
    __syncthreads();
  }

  const int mo = m0 + wr * 64 + ((lane >> 4) << 2);
  const int nn = n0 + wc * 64 + (lane & 15);
  float* Cb = Cout + (size_t)bz * strideC;
  const float* Rb = resid ? resid + (size_t)bz * strideC : nullptr;
#pragma unroll
  for (int i = 0; i < 4; ++i) {
#pragma unroll
    for (int j = 0; j < 4; ++j) {
      const int n = nn + j * 16;
#pragma unroll
      for (int reg = 0; reg < 4; ++reg) {
        const int m = mo + i * 16 + reg;
        float v = acc[i][j][reg];
        if (Rb) v += Rb[(size_t)m * ldc + n];
        Cb[(size_t)m * ldc + n] = v;
      }
    }
  }
}

// ---------------- row softmax: S fp32 [rows][512] -> P f16 -------------------
__global__ __launch_bounds__(256) void softmax_kernel(
    const float* __restrict__ S, f16_t* __restrict__ P) {
  const int row  = blockIdx.x * 4 + (threadIdx.x >> 6);
  const int lane = threadIdx.x & 63;
  const float* s = S + (size_t)row * 512;
  const float4 v0 = ((const float4*)s)[lane];
  const float4 v1 = ((const float4*)s)[64 + lane];
  float m = fmaxf(fmaxf(fmaxf(v0.x, v0.y), fmaxf(v0.z, v0.w)),
                  fmaxf(fmaxf(v1.x, v1.y), fmaxf(v1.z, v1.w)));
#pragma unroll
  for (int o = 32; o; o >>= 1) m = fmaxf(m, __shfl_xor(m, o, 64));
  float e[8];
  e[0] = __expf(v0.x - m); e[1] = __expf(v0.y - m);
  e[2] = __expf(v0.z - m); e[3] = __expf(v0.w - m);
  e[4] = __expf(v1.x - m); e[5] = __expf(v1.y - m);
  e[6] = __expf(v1.z - m); e[7] = __expf(v1.w - m);
  float sum = ((e[0] + e[1]) + (e[2] + e[3])) + ((e[4] + e[5]) + (e[6] + e[7]));
#pragma unroll
  for (int o = 32; o; o >>= 1) sum += __shfl_xor(sum, o, 64);
  const float r = 1.0f / sum;
  f16_t* p = P + (size_t)row * 512;
  f16x4 o0, o1;
  o0[0] = (f16_t)(e[0] * r); o0[1] = (f16_t)(e[1] * r);
  o0[2] = (f16_t)(e[2] * r); o0[3] = (f16_t)(e[3] * r);
  o1[0] = (f16_t)(e[4] * r); o1[1] = (f16_t)(e[5] * r);
  o1[2] = (f16_t)(e[6] * r); o1[3] = (f16_t)(e[7] * r);
  ((f16x4*)p)[lane] = o0;
  ((f16x4*)p)[64 + lane] = o1;
}

// -----------------------------------------------------------------------------
extern "C" void kernel_launch(void* const* d_in, const int* in_sizes, int n_in,
                              void* d_out, int out_size, void* d_ws, size_t ws_size,
                              hipStream_t stream) {
  (void)in_sizes; (void)n_in; (void)out_size;
  const float* x  = (const float*)d_in[0];
  const float* y  = (const float*)d_in[1];
  const float* wq = (const float*)d_in[2];
  const float* bq = (const float*)d_in[3];
  const float* wk = (const float*)d_in[4];
  const float* bk = (const float*)d_in[5];
  const float* wv = (const float*)d_in[6];
  const float* bv = (const float*)d_in[7];

  char* ws = (char*)d_ws;
  size_t off = 0;
  auto alloc = [&](size_t bytes) {
    void* p = ws + off;
    off = (off + bytes + 255) & ~(size_t)255;
    return p;
  };
  const size_t act_b  = (size_t)BATCH * NTOK * CCH * 2;     // 16 MB
  const size_t wt_b   = (size_t)27 * CCH * CCH * 2;         // 56.6 MB
  f16_t* x_t    = (f16_t*)alloc(act_b);
  f16_t* y_t    = (f16_t*)alloc(act_b);
  f16_t* wbuf   = (f16_t*)alloc(wt_b);
  f16_t* qb     = (f16_t*)alloc(act_b);
  f16_t* kb     = (f16_t*)alloc(act_b);
  f16_t* vb     = (f16_t*)alloc(act_b);
  float* scores = (float*)alloc((size_t)BATCH * 512 * 512 * 4);  // 16 MB
  f16_t* Pb     = (f16_t*)alloc((size_t)BATCH * 512 * 512 * 2);  //  8 MB
  f16_t* zerop  = (f16_t*)alloc(256);
  if (off > ws_size) return;  // workspace too small -> fail loudly via validation

  const dim3 blk(256);
  hipMemsetAsync(zerop, 0, 256, stream);
  cast_transpose_kernel<<<dim3(8, 16, 16), blk, 0, stream>>>(x, x_t);
  cast_transpose_kernel<<<dim3(8, 16, 16), blk, 0, stream>>>(y, y_t);

  // q = conv(x, wq) -> [B][N][C]
  wtrans_kernel<<<dim3(1024, 16), blk, 0, stream>>>(wq, wbuf);
  conv_gemm_kernel<<<dim3(64, 8), blk, 0, stream>>>(x_t, wbuf, bq, qb, 0, zerop);
  // k = conv(y, wk) -> [B][N][C]
  wtrans_kernel<<<dim3(1024, 16), blk, 0, stream>>>(wk, wbuf);
  conv_gemm_kernel<<<dim3(64, 8), blk, 0, stream>>>(y_t, wbuf, bk, kb, 0, zerop);
  // v = conv(y, wv) -> [B][C][N]
  wtrans_kernel<<<dim3(1024, 16), blk, 0, stream>>>(wv, wbuf);
  conv_gemm_kernel<<<dim3(64, 8), blk, 0, stream>>>(y_t, wbuf, bv, vb, 1, zerop);

  // scores[b][n][m] = sum_c q[b][n][c] * k[b][m][c]
  attn_gemm_kernel<<<dim3(4, 4, 16), blk, 0, stream>>>(
      qb, kb, scores, nullptr, 1024, 512,
      (size_t)512 * 1024, (size_t)512 * 1024, (size_t)512 * 512);
  // softmax rows
  softmax_kernel<<<dim3(BATCH * 512 / 4), blk, 0, stream>>>(scores, Pb);
  // out[b][c][n] = sum_m v[b][c][m] * P[b][n][m] + x[b][c][n]
  attn_gemm_kernel<<<dim3(4, 8, 16), blk, 0, stream>>>(
      vb, Pb, (float*)d_out, x, 512, 512,
      (size_t)1024 * 512, (size_t)512 * 512, (size_t)1024 * 512);
}

// Round 3
// 1596.896 us; speedup vs baseline: 1.2059x; 1.2059x over previous
//
#include <hip/hip_runtime.h>
#include <hip/hip_bf16.h>
#include <stdint.h>

// B=16, C=1024, D=H=W=8 -> N=512 tokens, 27 taps
#define BATCH 16
#define CCH   1024
#define NTOK  512
#define NKT   432   // K-tiles: 27 taps * (1024/64)

typedef _Float16 f16_t;
typedef f16_t f16x8 __attribute__((ext_vector_type(8)));
typedef f16_t f16x4 __attribute__((ext_vector_type(4)));
typedef float f32x4 __attribute__((ext_vector_type(4)));

#define GAS __attribute__((address_space(1)))
#define LAS __attribute__((address_space(3)))

__device__ __forceinline__ void gload_lds16(const void* g, void* l) {
  __builtin_amdgcn_global_load_lds((const GAS uint32_t*)g, (LAS uint32_t*)l, 16, 0, 0);
}

// ---------------- cast + transpose: [B][C][N] f32 -> [B][N][C] f16 -----------
__global__ __launch_bounds__(256) void cast_transpose_kernel(
    const float* __restrict__ src, f16_t* __restrict__ dst) {
  __shared__ float tile[64][65];
  const int b  = blockIdx.z;
  const int c0 = blockIdx.y * 64;
  const int n0 = blockIdx.x * 64;
  const int col  = threadIdx.x & 63;
  const int row4 = threadIdx.x >> 6;
  const float* s = src + ((size_t)b * CCH + c0) * NTOK + n0;
#pragma unroll
  for (int r = 0; r < 64; r += 4)
    tile[r + row4][col] = s[(size_t)(r + row4) * NTOK + col];
  __syncthreads();
  f16_t* d = dst + ((size_t)b * NTOK + n0) * CCH + c0;
#pragma unroll
  for (int r = 0; r < 64; r += 4)
    d[(size_t)(r + row4) * CCH + col] = (f16_t)tile[col][r + row4];
}

// -------- weight transpose: [O][I][27] f32 -> rows o_base+o of [27][3072][1024] f16
__global__ __launch_bounds__(256) void wtrans_kernel(
    const float* __restrict__ w, f16_t* __restrict__ wt, const int o_base) {
  __shared__ float buf[64 * 27];
  const int o  = blockIdx.x;
  const int i0 = blockIdx.y * 64;
  const float* s = w + (size_t)o * (CCH * 27) + (size_t)i0 * 27;
  for (int idx = threadIdx.x; idx < 64 * 27; idx += 256) buf[idx] = s[idx];
  __syncthreads();
  for (int idx = threadIdx.x; idx < 64 * 27; idx += 256) {
    const int t = idx >> 6;
    const int i = idx & 63;
    wt[((size_t)t * 3072 + o_base + o) * 1024 + i0 + i] = (f16_t)buf[i * 27 + t];
  }
}

// ---------------- fused QKV conv: 27*16 shifted GEMM K-tiles -----------------
// 256x256 tile, BK=64, 8 waves (2M x 4N), 8-phase (4/K-tile), counted vmcnt(6).
// LDS per set (64KB): [Ak0 16K][Ak1 16K][Bk0 16K][Bk1 16K]; 2 sets = 128KB.
// Swizzle: 16B slot s stored at lds-slot s ^ ((row>>1)&3) (source pre-swizzle).
__global__ __launch_bounds__(512, 2) void conv_fused_kernel(
    const f16_t* __restrict__ x_t, const f16_t* __restrict__ y_t,
    const f16_t* __restrict__ wcat, const float* __restrict__ bcat,
    f16_t* __restrict__ qb, f16_t* __restrict__ kb, f16_t* __restrict__ vb,
    const char* __restrict__ zp) {
  __shared__ char lds[131072];
  const int tid  = threadIdx.x;
  const int lane = tid & 63;
  const int wid  = tid >> 6;
  const int wr = wid >> 2, wc = wid & 3;

  // XCD-aware bijective swizzle (384 blocks, 384%8==0); same-XCD blocks share n_tile
  const int id = blockIdx.x;
  const int swz = (id & 7) * 48 + (id >> 3);
  const int n_tile = swz / 12, m_tile = swz % 12;
  const int m0  = m_tile * 256;          // fused C_out row base (0..3071)
  const int bn0 = n_tile * 256;
  const int b   = bn0 >> 9;
  const int n0  = bn0 & 511;
  const int sec = m_tile >> 2;           // 0=q,1=k,2=v
  const char* src_c = (const char*)((sec == 0) ? x_t : y_t) + (size_t)b * NTOK * 2048;
  const char* wcat_c = (const char*)wcat;

  // staging constants: thread covers (row = tid>>2 [+128], slot = tid&3)
  const int slotsrc16 = (((tid & 3) ^ ((tid >> 3) & 3)) << 4);
  const int tid16 = tid << 4;
  const int r0 = tid >> 2;
  const size_t arow0 = (size_t)(m0 + r0) * 2048 + slotsrc16;
  const size_t arow1 = arow0 + (size_t)128 * 2048;
  int cur_kt = -1;
  const char* bp0 = zp;
  const char* bp1 = zp;

  // fragment-read constants
  const int fr = lane & 15;
  const int rdbase = fr * 64 + ((((lane >> 4) ^ ((fr >> 1) & 3))) << 4);

  f32x4 acc[8][4] = {};

  auto stageA = [&](int tt, int kh) {
    const int te = (tt < NKT) ? tt : tt - 4;   // tail remap keeps vmcnt counts exact
    const size_t go = (size_t)(te >> 4) * (size_t)(3072 * 2048) +
                      ((size_t)(te & 15) << 7) + ((size_t)kh << 6);
    char* ldst = lds + (((te & 1) << 16) + (kh << 14)) + tid16;
    gload_lds16(wcat_c + go + arow0, ldst);
    gload_lds16(wcat_c + go + arow1, ldst + 8192);
  };
  auto upd_tap = [&](int kt) {
    cur_kt = kt;
    const int kd = kt / 9, rem = kt % 9, khh = rem / 3, kww = rem % 3;
#pragma unroll
    for (int l = 0; l < 2; ++l) {
      const int n = n0 + r0 + l * 128;
      const int d = (n >> 6) + kd - 1;
      const int h = ((n >> 3) & 7) + khh - 1;
      const int w = (n & 7) + kww - 1;
      const bool ok = ((unsigned)d < 8u) & ((unsigned)h < 8u) & ((unsigned)w < 8u);
      const int nsrc = (d << 6) + (h << 3) + w;
      const char* p = ok ? src_c + (size_t)nsrc * 2048 : zp;
      if (l == 0) bp0 = p; else bp1 = p;
    }
  };
  auto stageB = [&](int tt, int kh) {
    const int te = (tt < NKT) ? tt : tt - 4;
    const int kt = te >> 4;
    if (kt != cur_kt) upd_tap(kt);
    const int go = ((te & 15) << 7) + (kh << 6) + slotsrc16;
    char* ldst = lds + (((te & 1) << 16) + 32768 + (kh << 14)) + tid16;
    gload_lds16(bp0 + go, ldst);
    gload_lds16(bp1 + go, ldst + 8192);
  };

  // prologue: tile0 fully (8 instr), then Bk0/Bk1/Ak0 of tile1 (6 instr)
  stageA(0, 0); stageA(0, 1); stageB(0, 0); stageB(0, 1);
  stageB(1, 0); stageB(1, 1); stageA(1, 0);
  asm volatile("s_waitcnt vmcnt(6)\n\ts_barrier" ::: "memory");

#define MFMA16(IOFF, AV, BV)                                                   \
  _Pragma("unroll") for (int i = 0; i < 4; ++i) {                              \
    _Pragma("unroll") for (int j = 0; j < 4; ++j)                              \
        acc[IOFF + i][j] = __builtin_amdgcn_mfma_f32_16x16x32_f16(             \
            AV[i], BV[j], acc[IOFF + i][j], 0, 0, 0);                          \
  }

#pragma unroll 1
  for (int t = 0; t < NKT; ++t) {
    const int sbase = (t & 1) << 16;
    const char* sA = lds + sbase + wr * 8192 + rdbase;
    const char* sB = lds + sbase + 32768 + wc * 4096 + rdbase;
    f16x8 av0[4], av1[4], bv0[4], bv1[4];
    // ---- phase 0: rows i0-3 (k0) ; reads A03k0,A03k1,B(k0); stage Ak1(t+1)
#pragma unroll
    for (int i = 0; i < 4; ++i) av0[i] = *(const f16x8*)(sA + i * 1024);
#pragma unroll
    for (int i = 0; i < 4; ++i) av1[i] = *(const f16x8*)(sA + 16384 + i * 1024);
#pragma unroll
    for (int j = 0; j < 4; ++j) bv0[j] = *(const f16x8*)(sB + j * 1024);
    stageA(t + 1, 1);
    __builtin_amdgcn_s_barrier();
    __builtin_amdgcn_s_setprio(1);
    MFMA16(0, av0, bv0)
    __builtin_amdgcn_s_setprio(0);
    __builtin_amdgcn_s_barrier();
    // ---- phase 1: rows i0-3 (k1); reads B(k1); stage Bk0(t+2)
#pragma unroll
    for (int j = 0; j < 4; ++j) bv1[j] = *(const f16x8*)(sB + 16384 + j * 1024);
    stageB(t + 2, 0);
    __builtin_amdgcn_s_barrier();
    __builtin_amdgcn_s_setprio(1);
    MFMA16(0, av1, bv1)
    __builtin_amdgcn_s_setprio(0);
    __builtin_amdgcn_s_barrier();
    // ---- phase 2: rows i4-7 (k0); reads A47k0,A47k1; stage Bk1(t+2)
#pragma unroll
    for (int i = 0; i < 4; ++i) av0[i] = *(const f16x8*)(sA + 4096 + i * 1024);
#pragma unroll
    for (int i = 0; i < 4; ++i) av1[i] = *(const f16x8*)(sA + 16384 + 4096 + i * 1024);
    stageB(t + 2, 1);
    __builtin_amdgcn_s_barrier();
    __builtin_amdgcn_s_setprio(1);
    MFMA16(4, av0, bv0)
    __builtin_amdgcn_s_setprio(0);
    __builtin_amdgcn_s_barrier();
    // ---- phase 3: rows i4-7 (k1); stage Ak0(t+2); counted vmcnt at boundary
    stageA(t + 2, 0);
    __builtin_amdgcn_s_barrier();
    __builtin_amdgcn_s_setprio(1);
    MFMA16(4, av1, bv1)
    __builtin_amdgcn_s_setprio(0);
    asm volatile("s_waitcnt vmcnt(6)\n\ts_barrier" ::: "memory");
  }
#undef MFMA16

  // epilogue: C frag col=lane&15 -> token n, row=(lane>>4)*4+reg -> channel
  const int msec = (m_tile & 3) * 256;
  const int rq = (lane >> 4) << 2;
#pragma unroll
  for (int i = 0; i < 8; ++i) {
    const int cbase = msec + wr * 128 + i * 16 + rq;
    const float4 bs = *(const float4*)&bcat[m0 + wr * 128 + i * 16 + rq];
    if (sec < 2) {
      f16_t* out = (sec == 0) ? qb : kb;
#pragma unroll
      for (int j = 0; j < 4; ++j) {
        const int n = n0 + wc * 64 + j * 16 + fr;
        f16x4 pk;
        pk[0] = (f16_t)(acc[i][j][0] + bs.x);
        pk[1] = (f16_t)(acc[i][j][1] + bs.y);
        pk[2] = (f16_t)(acc[i][j][2] + bs.z);
        pk[3] = (f16_t)(acc[i][j][3] + bs.w);
        *(f16x4*)(out + ((size_t)(b * NTOK + n)) * CCH + cbase) = pk;
      }
    } else {
      const float bb[4] = {bs.x, bs.y, bs.z, bs.w};
#pragma unroll
      for (int reg = 0; reg < 4; ++reg) {
        f16_t* dst = vb + ((size_t)b * CCH + cbase + reg) * NTOK;
#pragma unroll
        for (int j = 0; j < 4; ++j) {
          const int n = n0 + wc * 64 + j * 16 + fr;
          dst[n] = (f16_t)(acc[i][j][reg] + bb[reg]);
        }
      }
    }
  }
}

// ---------------- generic gemm_bt for attention: C = A * Bt^T (+resid) -------
__global__ __launch_bounds__(256) void attn_gemm_kernel(
    const f16_t* __restrict__ A, const f16_t* __restrict__ Bt,
    float* __restrict__ Cout, const float* __restrict__ resid,
    const int Kdim, const int ldc,
    const size_t strideA, const size_t strideB, const size_t strideC) {
  __shared__ f16_t As[128 * 64];
  __shared__ f16_t Bs[128 * 64];
  char* As_c = (char*)As;
  char* Bs_c = (char*)Bs;

  const int tid  = threadIdx.x;
  const int lane = tid & 63;
  const int wave = tid >> 6;
  const int wr = wave >> 1, wc = wave & 1;
  const int bz = blockIdx.z;
  const int m0 = blockIdx.y * 128;
  const int n0 = blockIdx.x * 128;

  const f16_t* Ab = A + (size_t)bz * strideA;
  const f16_t* Bb = Bt + (size_t)bz * strideB;

  const int rowb = tid >> 3;
  const int colb = (tid & 7) * 16;

  const char* ap[4];
  const char* bp[4];
#pragma unroll
  for (int r = 0; r < 4; ++r) {
    const int row = r * 32 + rowb;
    ap[r] = (const char*)(Ab + (size_t)(m0 + row) * Kdim) + colb;
    bp[r] = (const char*)(Bb + (size_t)(n0 + row) * Kdim) + colb;
  }

  f32x4 acc[4][4] = {};
  const int fr = lane & 15;
  const int fk = (lane >> 4) << 3;

  for (int k0 = 0; k0 < Kdim; k0 += 64) {
#pragma unroll
    for (int r = 0; r < 4; ++r)
      gload_lds16(ap[r], As_c + r * 4096 + wave * 1024);
#pragma unroll
    for (int r = 0; r < 4; ++r)
      gload_lds16(bp[r], Bs_c + r * 4096 + wave * 1024);
#pragma unroll
    for (int r = 0; r < 4; ++r) { ap[r] += 128; bp[r] += 128; }
    __syncthreads();
#pragma unroll
    for (int ks = 0; ks < 2; ++ks) {
      const int kc = ks * 32 + fk;
      f16x8 av[4], bv[4];
#pragma unroll
      for (int i = 0; i < 4; ++i)
        av[i] = *(const f16x8*)&As[(wr * 64 + i * 16 + fr) * 64 + kc];
#pragma unroll
      for (int i = 0; i < 4; ++i)
        bv[i] = *(const f16x8*)&Bs[(wc * 64 + i * 16 + fr) * 64 + kc];
#pragma unroll
      for (int i = 0; i < 4; ++i)
#pragma unroll
        for (int j = 0; j < 4; ++j)
          acc[i][j] = __builtin_amdgcn_mfma_f32_16x16x32_f16(av[i], bv[j], acc[i][j], 0, 0, 0);
    }
    __syncthreads();
  }

  const int mo = m0 + wr * 64 + ((lane >> 4) << 2);
  const int nn = n0 + wc * 64 + (lane & 15);
  float* Cb = Cout + (size_t)bz * strideC;
  const float* Rb = resid ? resid + (size_t)bz * strideC : nullptr;
#pragma unroll
  for (int i = 0; i < 4; ++i) {
#pragma unroll
    for (int j = 0; j < 4; ++j) {
      const int n = nn + j * 16;
#pragma unroll
      for (int reg = 0; reg < 4; ++reg) {
        const int m = mo + i * 16 + reg;
        float v = acc[i][j][reg];
        if (Rb) v += Rb[(size_t)m * ldc + n];
        Cb[(size_t)m * ldc + n] = v;
      }
    }
  }
}

// ---------------- row softmax: S fp32 [rows][512] -> P f16 -------------------
__global__ __launch_bounds__(256) void softmax_kernel(
    const float* __restrict__ S, f16_t* __restrict__ P) {
  const int row  = blockIdx.x * 4 + (threadIdx.x >> 6);
  const int lane = threadIdx.x & 63;
  const float* s = S + (size_t)row * 512;
  const float4 v0 = ((const float4*)s)[lane];
  const float4 v1 = ((const float4*)s)[64 + lane];
  float m = fmaxf(fmaxf(fmaxf(v0.x, v0.y), fmaxf(v0.z, v0.w)),
                  fmaxf(fmaxf(v1.x, v1.y), fmaxf(v1.z, v1.w)));
#pragma unroll
  for (int o = 32; o; o >>= 1) m = fmaxf(m, __shfl_xor(m, o, 64));
  float e[8];
  e[0] = __expf(v0.x - m); e[1] = __expf(v0.y - m);
  e[2] = __expf(v0.z - m); e[3] = __expf(v0.w - m);
  e[4] = __expf(v1.x - m); e[5] = __expf(v1.y - m);
  e[6] = __expf(v1.z - m); e[7] = __expf(v1.w - m);
  float sum = ((e[0] + e[1]) + (e[2] + e[3])) + ((e[4] + e[5]) + (e[6] + e[7]));
#pragma unroll
  for (int o = 32; o; o >>= 1) sum += __shfl_xor(sum, o, 64);
  const float r = 1.0f / sum;
  f16_t* p = P + (size_t)row * 512;
  f16x4 o0, o1;
  o0[0] = (f16_t)(e[0] * r); o0[1] = (f16_t)(e[1] * r);
  o0[2] = (f16_t)(e[2] * r); o0[3] = (f16_t)(e[3] * r);
  o1[0] = (f16_t)(e[4] * r); o1[1] = (f16_t)(e[5] * r);
  o1[2] = (f16_t)(e[6] * r); o1[3] = (f16_t)(e[7] * r);
  ((f16x4*)p)[lane] = o0;
  ((f16x4*)p)[64 + lane] = o1;
}

// -----------------------------------------------------------------------------
extern "C" void kernel_launch(void* const* d_in, const int* in_sizes, int n_in,
                              void* d_out, int out_size, void* d_ws, size_t ws_size,
                              hipStream_t stream) {
  (void)in_sizes; (void)n_in; (void)out_size;
  const float* x  = (const float*)d_in[0];
  const float* y  = (const float*)d_in[1];
  const float* wq = (const float*)d_in[2];
  const float* bq = (const float*)d_in[3];
  const float* wk = (const float*)d_in[4];
  const float* bk = (const float*)d_in[5];
  const float* wv = (const float*)d_in[6];
  const float* bv = (const float*)d_in[7];

  char* ws = (char*)d_ws;
  size_t off = 0;
  auto alloc = [&](size_t bytes) {
    void* p = ws + off;
    off = (off + bytes + 255) & ~(size_t)255;
    return p;
  };
  const size_t act_b = (size_t)BATCH * NTOK * CCH * 2;  // 16 MB
  f16_t* x_t    = (f16_t*)alloc(act_b);
  f16_t* y_t    = (f16_t*)alloc(act_b);
  f16_t* wcat   = (f16_t*)alloc((size_t)27 * 3072 * 1024 * 2);   // 170 MB
  float* bcat   = (float*)alloc(3072 * 4);
  f16_t* qb     = (f16_t*)alloc(act_b);
  f16_t* kb     = (f16_t*)alloc(act_b);
  f16_t* vb     = (f16_t*)alloc(act_b);
  float* scores = (float*)alloc((size_t)BATCH * 512 * 512 * 4);  // 16 MB
  f16_t* Pb     = (f16_t*)alloc((size_t)BATCH * 512 * 512 * 2);  //  8 MB
  char*  zerop  = (char*)alloc(4096);
  if (off > ws_size) return;

  const dim3 blk(256);
  hipMemsetAsync(zerop, 0, 4096, stream);
  cast_transpose_kernel<<<dim3(8, 16, 16), blk, 0, stream>>>(x, x_t);
  cast_transpose_kernel<<<dim3(8, 16, 16), blk, 0, stream>>>(y, y_t);

  wtrans_kernel<<<dim3(1024, 16), blk, 0, stream>>>(wq, wcat, 0);
  wtrans_kernel<<<dim3(1024, 16), blk, 0, stream>>>(wk, wcat, 1024);
  wtrans_kernel<<<dim3(1024, 16), blk, 0, stream>>>(wv, wcat, 2048);
  hipMemcpyAsync(bcat,        bq, 1024 * 4, hipMemcpyDeviceToDevice, stream);
  hipMemcpyAsync(bcat + 1024, bk, 1024 * 4, hipMemcpyDeviceToDevice, stream);
  hipMemcpyAsync(bcat + 2048, bv, 1024 * 4, hipMemcpyDeviceToDevice, stream);

  conv_fused_kernel<<<dim3(384), dim3(512), 0, stream>>>(
      x_t, y_t, wcat, bcat, qb, kb, vb, zerop);

  // scores[b][n][m] = sum_c q[b][n][c] * k[b][m][c]
  attn_gemm_kernel<<<dim3(4, 4, 16), blk, 0, stream>>>(
      qb, kb, scores, nullptr, 1024, 512,
      (size_t)512 * 1024, (size_t)512 * 1024, (size_t)512 * 512);
  softmax_kernel<<<dim3(BATCH * 512 / 4), blk, 0, stream>>>(scores, Pb);
  // out[b][c][n] = sum_m v[b][c][m] * P[b][n][m] + x[b][c][n]
  attn_gemm_kernel<<<dim3(4, 8, 16), blk, 0, stream>>>(
      vb, Pb, (float*)d_out, x, 512, 512,
      (size_t)1024 * 512, (size_t)512 * 512, (size_t)1024 * 512);
}